// Round 3
// baseline (276.580 us; speedup 1.0000x reference)
//
#include <hip/hip_runtime.h>
#include <hip/hip_bf16.h>

// Problem constants
constexpr int Bc = 32, Sc = 4096, Dc = 64, Pc = 8, STRIDEc = 4, Hc = 512;
constexpr int Tc = (Sc - Pc) / STRIDEc + 1;   // 1023
constexpr int Kc = Pc * Dc;                   // 512
constexpr float EPSc = 1e-6f;
constexpr int APITCH = 520;                   // shorts/row: 1040B rows, balanced banks
constexpr int BM = 32;                        // rows per tile
constexpr int NTILE = 32 * Bc;                // 32 t-tiles x 32 batches = 1024
constexpr size_t WT_BYTES = 512 * 512 * 2;    // 512 KB

typedef __bf16 bf16x8 __attribute__((ext_vector_type(8)));
typedef unsigned short ushort8 __attribute__((ext_vector_type(8)));
typedef float f32x4 __attribute__((ext_vector_type(4)));

__device__ __forceinline__ int n_tok_of(int len) {
    return (len >= Pc) ? ((len - Pc) / STRIDEc + 1) : 1;
}

// fp32 -> bf16 round-to-nearest-even
__device__ __forceinline__ unsigned short f2bf(float f) {
    unsigned u = __builtin_bit_cast(unsigned, f);
    u = (u + 0x7FFFu + ((u >> 16) & 1u)) >> 16;
    return (unsigned short)u;
}

// ---------------------------------------------------------------------------
// Prep: Wt_s[k0/32][n][k%32] = bf16(W[k][n]) (k-slice-packed, fragment-
// contiguous), token_lengths, PLUS: reset the work-steal counter and
// precompute cvec[512] = scale * bias * rsqrt(mean(bias^2)+eps)  (the
// constant hidden row for all-padding tiles).
// ---------------------------------------------------------------------------
__global__ __launch_bounds__(256) void prep_kernel(
        const float* __restrict__ W, const int* __restrict__ lengths,
        const float* __restrict__ bias, const float* __restrict__ scale,
        unsigned short* __restrict__ Wt, float* __restrict__ cvec,
        int* __restrict__ ctr, float* __restrict__ out_tl) {
    __shared__ float tile[32][33];
    const int k0 = blockIdx.x * 32, n0 = blockIdx.y * 32;
    const int r = threadIdx.x >> 3, c = (threadIdx.x & 7) * 4;
    const float4 v = *(const float4*)(W + (size_t)(k0 + r) * Hc + n0 + c);
    tile[c + 0][r] = v.x;
    tile[c + 1][r] = v.y;
    tile[c + 2][r] = v.z;
    tile[c + 3][r] = v.w;
    __syncthreads();
    ushort4 o;
    o.x = f2bf(tile[r][c + 0]);
    o.y = f2bf(tile[r][c + 1]);
    o.z = f2bf(tile[r][c + 2]);
    o.w = f2bf(tile[r][c + 3]);
    *(ushort4*)(Wt + (size_t)blockIdx.x * (Hc * 32) + (size_t)(n0 + r) * 32 + c) = o;

    if (blockIdx.x == 0 && blockIdx.y == 0) {
        const int tid = threadIdx.x;
        if (tid == 0) *ctr = 0;
        if (tid < Bc) out_tl[tid] = (float)n_tok_of(lengths[tid]);
        // cvec: 256 threads x 2 elements
        __shared__ float red[4];
        const int w = tid >> 6, lane = tid & 63;
        const float2 b2 = *(const float2*)(bias + tid * 2);
        float s = b2.x * b2.x + b2.y * b2.y;
#pragma unroll
        for (int off = 32; off; off >>= 1) s += __shfl_xor(s, off);
        if (lane == 0) red[w] = s;
        __syncthreads();
        const float rstd0 = rsqrtf((red[0] + red[1] + red[2] + red[3])
                                   * (1.0f / (float)Hc) + EPSc);
        const float2 s2 = *(const float2*)(scale + tid * 2);
        float2 cv;
        cv.x = b2.x * rstd0 * s2.x;
        cv.y = b2.y * rstd0 * s2.y;
        *(float2*)(cvec + tid * 2) = cv;
    }
}

// ---------------------------------------------------------------------------
// Fused, persistent-block work-stealing version.
//   * 512 persistent blocks (2/CU) pull tiles from an atomic counter over
//     1024 tiles (BM=32 x 32 batches), ordered t0-ascending so heavy (GEMM)
//     tiles run first and cheap padding tiles form the balancing tail.
//     This fixes r1/r2's static 2-blocks-per-CU makespan imbalance (fast-path
//     blocks freed CUs with nothing left to run).
//   * Heavy tile: phase1 stream 32 rows -> tokens + bf16 LDS (1 barrier),
//     phase2 barrier-free 16 k-steps (Wt fragments reg-double-buffered from
//     L2), epilogue bias+RMS+scale.
//   * Light tile: pure streaming of precomputed cvec + zeros (no reduction).
// ---------------------------------------------------------------------------
__global__ __launch_bounds__(256, 2) void fused_kernel(
        const float* __restrict__ x, const int* __restrict__ lengths,
        const unsigned short* __restrict__ Wt, const float* __restrict__ bias,
        const float* __restrict__ scale, const float* __restrict__ cvec,
        int* __restrict__ ctr, float* __restrict__ hidden,
        float* __restrict__ tokens) {
    __shared__ unsigned short As[BM * APITCH];   // 33,280 B
    __shared__ float ssbuf[4][BM];
    __shared__ int sIdx;

    const int tid  = threadIdx.x;
    const int w    = tid >> 6;
    const int lane = tid & 63;
    const int l15  = lane & 15;
    const int quad = lane >> 4;

    // Per-lane B-fragment base (fragment (w,ct,l15,quad) contiguous in Wt).
    const unsigned short* wfrag = Wt + ((w * 128 + l15) * 32 + quad * 8);

    for (;;) {
        if (tid == 0) sIdx = atomicAdd(ctr, 1);
        __syncthreads();                          // also the As/ssbuf reuse fence
        const int idx = sIdx;
        if (idx >= NTILE) return;

        const int b    = idx & 31;
        const int t0   = (idx >> 5) * BM;
        const int ntok = n_tok_of(lengths[b]);
        float* tokb = tokens + ((size_t)b * Tc + t0) * Kc;

        if (t0 >= ntok) {
            // ---- light tile: stream constant row + zeros ----
            const int c4 = (tid & 127) * 4;
            const f32x4 cv = *(const f32x4*)(cvec + c4);
            const f32x4 z  = {0.f, 0.f, 0.f, 0.f};
            float* hidb = hidden + ((size_t)b * Tc + t0) * Hc;
            const int r0 = tid >> 7;              // 0 or 1
#pragma unroll
            for (int rr = r0; rr < BM; rr += 2) {
                if (t0 + rr < Tc) {
                    __builtin_nontemporal_store(cv, (f32x4*)(hidb + (size_t)rr * Hc + c4));
                    __builtin_nontemporal_store(z,  (f32x4*)(tokb + (size_t)rr * Kc + c4));
                }
            }
            __syncthreads();                      // all read sIdx before next overwrite
            continue;
        }

        // ---- heavy tile ----
        const float* xb = x + ((size_t)b * Sc + (size_t)t0 * STRIDEc) * Dc;

        ushort8 rbA[8], rbB[8];
#pragma unroll
        for (int ct = 0; ct < 8; ++ct)            // slice-0 fragments (L2)
            rbA[ct] = *(const ushort8*)(wfrag + ct * 512);

        // phase 1: stream 32 rows x 512 f32 -> tokens + LDS. 16 chunks/thread.
#pragma unroll 8
        for (int it = 0; it < 16; ++it) {
            const int c   = tid + it * 256;
            const int r   = c >> 7;               // 0..31
            const int col = (c & 127) * 4;
            const int t   = t0 + r;
            f32x4 v = {0.f, 0.f, 0.f, 0.f};
            if (t < ntok) v = *(const f32x4*)(xb + (size_t)r * Kc + col);
            if (t < Tc)
                __builtin_nontemporal_store(v, (f32x4*)(tokb + (size_t)r * Kc + col));
            ushort4 h4;
            h4.x = f2bf(v[0]); h4.y = f2bf(v[1]); h4.z = f2bf(v[2]); h4.w = f2bf(v[3]);
            *(ushort4*)(As + r * APITCH + col) = h4;
        }
        __syncthreads();

        // phase 2: barrier-free k-loop, Wt fragments reg ping-pong from L2.
        f32x4 acc[2][8];
#pragma unroll
        for (int tt = 0; tt < 2; ++tt)
#pragma unroll
            for (int ct = 0; ct < 8; ++ct) acc[tt][ct] = (f32x4){0.f, 0.f, 0.f, 0.f};

        auto do_step = [&](const int step, ushort8 (&rbC)[8], ushort8 (&rbN)[8]) {
            const int k0 = step * 32;
            bf16x8 btok[2];
#pragma unroll
            for (int tt = 0; tt < 2; ++tt)
                btok[tt] = __builtin_bit_cast(bf16x8,
                    *(const ushort8*)(As + (tt * 16 + l15) * APITCH + k0 + quad * 8));
            if (step < 15) {
                const unsigned short* wn = wfrag + (size_t)(step + 1) * (Hc * 32);
#pragma unroll
                for (int ct = 0; ct < 8; ++ct)
                    rbN[ct] = *(const ushort8*)(wn + ct * 512);
            }
#pragma unroll
            for (int ct = 0; ct < 8; ++ct) {
                const bf16x8 aW = __builtin_bit_cast(bf16x8, rbC[ct]);
#pragma unroll
                for (int tt = 0; tt < 2; ++tt)
                    acc[tt][ct] = __builtin_amdgcn_mfma_f32_16x16x32_bf16(
                        aW, btok[tt], acc[tt][ct], 0, 0, 0);
            }
        };
#pragma unroll
        for (int sp = 0; sp < 8; ++sp) {
            do_step(2 * sp,     rbA, rbB);
            do_step(2 * sp + 1, rbB, rbA);
        }

        // epilogue: bias, in-register row sums, RMS, scale, nt stores
        float ss[2] = {0.f, 0.f};
#pragma unroll
        for (int ct = 0; ct < 8; ++ct) {
            const f32x4 b4 = *(const f32x4*)(bias + w * 128 + ct * 16 + quad * 4);
#pragma unroll
            for (int tt = 0; tt < 2; ++tt) {
                f32x4 h = acc[tt][ct] + b4;
                acc[tt][ct] = h;
                ss[tt] += h[0] * h[0] + h[1] * h[1] + h[2] * h[2] + h[3] * h[3];
            }
        }
#pragma unroll
        for (int tt = 0; tt < 2; ++tt) {
            float s = ss[tt];
            s += __shfl_xor(s, 16);
            s += __shfl_xor(s, 32);
            if (quad == 0) ssbuf[w][tt * 16 + l15] = s;
        }
        __syncthreads();
        float rstd[2];
#pragma unroll
        for (int tt = 0; tt < 2; ++tt) {
            const int r = tt * 16 + l15;
            const float tot = ssbuf[0][r] + ssbuf[1][r] + ssbuf[2][r] + ssbuf[3][r];
            rstd[tt] = rsqrtf(tot * (1.0f / (float)Hc) + EPSc);
        }
#pragma unroll
        for (int ct = 0; ct < 8; ++ct) {
            const f32x4 s4 = *(const f32x4*)(scale + w * 128 + ct * 16 + quad * 4);
#pragma unroll
            for (int tt = 0; tt < 2; ++tt) {
                const int t = t0 + tt * 16 + l15;
                if (t < Tc) {
                    f32x4 o = acc[tt][ct] * rstd[tt] * s4;
                    __builtin_nontemporal_store(o,
                        (f32x4*)(hidden + ((size_t)b * Tc + t) * Hc
                                 + w * 128 + ct * 16 + quad * 4));
                }
            }
        }
    }
}

extern "C" void kernel_launch(void* const* d_in, const int* in_sizes, int n_in,
                              void* d_out, int out_size, void* d_ws, size_t ws_size,
                              hipStream_t stream) {
    const float* x       = (const float*)d_in[0];
    const int*   lengths = (const int*)d_in[1];
    const float* W       = (const float*)d_in[2];
    const float* bias    = (const float*)d_in[3];
    const float* scale   = (const float*)d_in[4];

    const size_t BTH = (size_t)Bc * Tc * Hc;   // 16,760,832
    float* out    = (float*)d_out;
    float* hidden = out;                        // output 0
    float* tl     = out + BTH;                  // output 1 (32 floats)
    float* tokens = out + BTH + Bc;             // output 2

    // workspace layout: Wt (512 KB) | ctr (int, 64B-aligned slot) | cvec (2 KB)
    unsigned short* Wt = (unsigned short*)d_ws;
    int*   ctr  = (int*)((char*)d_ws + WT_BYTES);
    float* cvec = (float*)((char*)d_ws + WT_BYTES + 64);

    {   // W -> Wt, token_lengths, counter reset, cvec precompute
        dim3 grid(Hc / 32, Hc / 32);            // (16,16)
        prep_kernel<<<grid, 256, 0, stream>>>(W, lengths, bias, scale,
                                              Wt, cvec, ctr, tl);
    }
    {   // persistent work-stealing fused kernel: 512 blocks (2/CU)
        fused_kernel<<<dim3(512), 256, 0, stream>>>(x, lengths, Wt, bias, scale,
                                                    cvec, ctr, hidden, tokens);
    }
}

// Round 4
// 185.836 us; speedup vs baseline: 1.4883x; 1.4883x over previous
//
#include <hip/hip_runtime.h>
#include <hip/hip_bf16.h>

// Problem constants
constexpr int Bc = 32, Sc = 4096, Dc = 64, Pc = 8, STRIDEc = 4, Hc = 512;
constexpr int Tc = (Sc - Pc) / STRIDEc + 1;   // 1023
constexpr int Kc = Pc * Dc;                   // 512
constexpr float EPSc = 1e-6f;
constexpr int PITCH = 40;                     // bf16 LDS row pitch (80B -> 2-way banks = free)

typedef __bf16 bf16x8 __attribute__((ext_vector_type(8)));
typedef unsigned short ushort8 __attribute__((ext_vector_type(8)));
typedef float f32x4 __attribute__((ext_vector_type(4)));

__device__ __forceinline__ int n_tok_of(int len) {
    return (len >= Pc) ? ((len - Pc) / STRIDEc + 1) : 1;
}

// fp32 -> bf16 round-to-nearest-even
__device__ __forceinline__ unsigned short f2bf(float f) {
    unsigned u = __builtin_bit_cast(unsigned, f);
    u = (u + 0x7FFFu + ((u >> 16) & 1u)) >> 16;
    return (unsigned short)u;
}

// ---------------------------------------------------------------------------
// Prep: Wt_s[k0/32][n][k%32] = bf16(W[k][n])  (transposed, k-slice-packed so
// each k-step's B tile is one contiguous 32 KB block), + token_lengths.
// grid (16,16) tiles of 32x32, 256 threads.
// ---------------------------------------------------------------------------
__global__ __launch_bounds__(256) void prep_kernel(
        const float* __restrict__ W, const int* __restrict__ lengths,
        unsigned short* __restrict__ Wt, float* __restrict__ out_tl) {
    __shared__ float tile[32][33];
    const int k0 = blockIdx.x * 32, n0 = blockIdx.y * 32;
    const int r = threadIdx.x >> 3, c = (threadIdx.x & 7) * 4;
    const float4 v = *(const float4*)(W + (size_t)(k0 + r) * Hc + n0 + c);
    tile[c + 0][r] = v.x;
    tile[c + 1][r] = v.y;
    tile[c + 2][r] = v.z;
    tile[c + 3][r] = v.w;
    __syncthreads();
    ushort4 o;
    o.x = f2bf(tile[r][c + 0]);
    o.y = f2bf(tile[r][c + 1]);
    o.z = f2bf(tile[r][c + 2]);
    o.w = f2bf(tile[r][c + 3]);
    // slice = blockIdx.x; within slice: n-major, 32 k's per row
    *(ushort4*)(Wt + (size_t)blockIdx.x * (Hc * 32) + (size_t)(n0 + r) * 32 + c) = o;
    if (blockIdx.x == 0 && blockIdx.y == 0 && threadIdx.x < Bc)
        out_tl[threadIdx.x] = (float)n_tok_of(lengths[threadIdx.x]);
}

// ---------------------------------------------------------------------------
// Fused: tokens-write + bf16-MFMA GEMM (BM=64 x BN=512) + bias + RMSNorm*scale.
// EXACT r0 structure (best measured: 181 us): B staged through LDS, tokens
// stores spread across the k-loop, 2 barriers/step, software-pipelined,
// regular (cached) stores. Three minimal deltas:
//  * Balanced static tile remap: t0 = (b&16 ? 15-bx : bx)*64. Blocks (bx,b)
//    and (bx,b+16) share a CU; remap gives that CU one mostly-heavy + one
//    mostly-light tile instead of two identical-bx tiles (makespan 2H -> H+L).
//  * All-padding fast path (t0 >= ntok): hidden = scale*b/rms(b), tokens = 0.
//  * Dead per-element mask removed: t < ntok implies pos < len (len >= P).
// ---------------------------------------------------------------------------
__global__ __launch_bounds__(256, 2) void fused_kernel(
        const float* __restrict__ x, const int* __restrict__ lengths,
        const unsigned short* __restrict__ Wt, const float* __restrict__ bias,
        const float* __restrict__ scale, float* __restrict__ hidden,
        float* __restrict__ tokens) {
    const int b  = blockIdx.y;
    const int t0 = ((b & 16) ? (15 - (int)blockIdx.x) : (int)blockIdx.x) * 64;
    const int len = lengths[b];
    const int ntok = n_tok_of(len);
    const int tid = threadIdx.x;

    float* tokb = tokens + (size_t)b * Tc * Kc;

    if (t0 >= ntok) {
        // ---- fast path: every row in this block is padding ----
        // hidden row = scale * b / rms(b)  (== GEMM path on zero rows)
        __shared__ float red[4];
        const int w = tid >> 6, lane = tid & 63;
        const float2 b2 = *(const float2*)(bias + tid * 2);
        float s = b2.x * b2.x + b2.y * b2.y;
#pragma unroll
        for (int off = 32; off; off >>= 1) s += __shfl_xor(s, off);
        if (lane == 0) red[w] = s;
        __syncthreads();
        const float rstd0 = rsqrtf((red[0] + red[1] + red[2] + red[3])
                                   * (1.0f / (float)Hc) + EPSc);
        const int c4 = (tid & 127) * 4;
        const f32x4 cvec = *(const f32x4*)(bias + c4) * rstd0
                         * *(const f32x4*)(scale + c4);
        const f32x4 z = {0.f, 0.f, 0.f, 0.f};
        float* hidb = hidden + ((size_t)b * Tc + t0) * Hc;
        float* tokp = tokb + (size_t)t0 * Kc;
        const int r0 = tid >> 7;                 // 0 or 1: two rows per pass
#pragma unroll 8
        for (int rr = r0; rr < 64; rr += 2) {
            if (t0 + rr < Tc) {
                __builtin_nontemporal_store(cvec, (f32x4*)(hidb + (size_t)rr * Hc + c4));
                __builtin_nontemporal_store(z,    (f32x4*)(tokp + (size_t)rr * Kc + c4));
            }
        }
        return;
    }

    __shared__ unsigned short As[64 * PITCH];    // As[r][k], bf16 (token tile)
    __shared__ unsigned short Bs[512 * PITCH];   // Bs[n][k], bf16 (Wt tile)
    __shared__ float ssbuf[4][64];

    const int w    = tid >> 6;
    const int lane = tid & 63;
    const int l15  = lane & 15;
    const int quad = lane >> 4;

    f32x4 acc[4][8];                             // [ttile][ctile]
#pragma unroll
    for (int tt = 0; tt < 4; ++tt)
#pragma unroll
        for (int ct = 0; ct < 8; ++ct) acc[tt][ct] = (f32x4){0.f, 0.f, 0.f, 0.f};

    const float* xb = x + (size_t)b * (Sc * Dc);

    // Per-thread staging coordinates (A: 2 float4 chunks; B: 8 ushort8 chunks)
    int   a_r[2], a_c[2];  bool a_tv[2], a_lv[2];  const float* a_src[2];
#pragma unroll
    for (int it = 0; it < 2; ++it) {
        const int l = tid + it * 256;
        a_r[it] = l >> 3;                        // row in tile (0..63)
        a_c[it] = (l & 7) * 4;                   // k offset within 32-k tile
        const int t = t0 + a_r[it];
        a_tv[it] = (t < Tc);
        a_lv[it] = (t < ntok);                   // row fully valid iff t < ntok
        a_src[it] = xb + (size_t)t * (STRIDEc * Dc);
    }

    float4  ra[2];
    ushort8 rb[8];

    // ---- prologue loads (k0 = 0) ----
#pragma unroll
    for (int it = 0; it < 2; ++it) {
        ra[it] = make_float4(0.f, 0.f, 0.f, 0.f);
        if (a_lv[it]) ra[it] = *(const float4*)(a_src[it] + a_c[it]);
    }
#pragma unroll
    for (int it = 0; it < 8; ++it)
        rb[it] = *(const ushort8*)(Wt + (size_t)(tid + it * 256) * 8);

    for (int step = 0; step < 16; ++step) {
        const int k0 = step * 32;
        if (step) __syncthreads();               // previous MFMA reads done

        // ---- commit staged regs to LDS (+ tokens out) ----
#pragma unroll
        for (int it = 0; it < 2; ++it) {
            const float4 v = ra[it];
            if (a_tv[it])
                *(float4*)(tokb + (size_t)(t0 + a_r[it]) * Kc + k0 + a_c[it]) = v;
            ushort4 h4;
            h4.x = f2bf(v.x); h4.y = f2bf(v.y); h4.z = f2bf(v.z); h4.w = f2bf(v.w);
            *(ushort4*)(As + a_r[it] * PITCH + a_c[it]) = h4;
        }
#pragma unroll
        for (int it = 0; it < 8; ++it) {
            const int cc = tid + it * 256;
            *(ushort8*)(Bs + (cc >> 2) * PITCH + (cc & 3) * 8) = rb[it];
        }
        __syncthreads();

        // ---- prefetch next tile while MFMA runs ----
        if (step < 15) {
            const int kn = k0 + 32;
#pragma unroll
            for (int it = 0; it < 2; ++it) {
                ra[it] = make_float4(0.f, 0.f, 0.f, 0.f);
                if (a_lv[it]) ra[it] = *(const float4*)(a_src[it] + kn + a_c[it]);
            }
            const unsigned short* wsrc = Wt + (size_t)(step + 1) * (Hc * 32);
#pragma unroll
            for (int it = 0; it < 8; ++it)
                rb[it] = *(const ushort8*)(wsrc + (size_t)(tid + it * 256) * 8);
        }

        // ---- MFMA (operand-swapped) ----
        bf16x8 btok[4];
#pragma unroll
        for (int tt = 0; tt < 4; ++tt)
            btok[tt] = __builtin_bit_cast(bf16x8,
                *(const ushort8*)(As + (tt * 16 + l15) * PITCH + quad * 8));
#pragma unroll
        for (int ct = 0; ct < 8; ++ct) {
            bf16x8 aW = __builtin_bit_cast(bf16x8,
                *(const ushort8*)(Bs + (w * 128 + ct * 16 + l15) * PITCH + quad * 8));
#pragma unroll
            for (int tt = 0; tt < 4; ++tt)
                acc[tt][ct] = __builtin_amdgcn_mfma_f32_16x16x32_bf16(
                    aW, btok[tt], acc[tt][ct], 0, 0, 0);
        }
    }

    // ---- epilogue: bias, in-register row sums, RMS, scale, float4 stores ----
    float ss[4] = {0.f, 0.f, 0.f, 0.f};
#pragma unroll
    for (int ct = 0; ct < 8; ++ct) {
        const f32x4 b4 = *(const f32x4*)(bias + w * 128 + ct * 16 + quad * 4);
#pragma unroll
        for (int tt = 0; tt < 4; ++tt) {
            f32x4 h = acc[tt][ct] + b4;
            acc[tt][ct] = h;
            ss[tt] += h[0] * h[0] + h[1] * h[1] + h[2] * h[2] + h[3] * h[3];
        }
    }
#pragma unroll
    for (int tt = 0; tt < 4; ++tt) {
        float s = ss[tt];
        s += __shfl_xor(s, 16);
        s += __shfl_xor(s, 32);
        if (quad == 0) ssbuf[w][tt * 16 + l15] = s;
    }
    __syncthreads();
    float rstd[4];
#pragma unroll
    for (int tt = 0; tt < 4; ++tt) {
        const int r = tt * 16 + l15;
        const float tot = ssbuf[0][r] + ssbuf[1][r] + ssbuf[2][r] + ssbuf[3][r];
        rstd[tt] = rsqrtf(tot * (1.0f / (float)Hc) + EPSc);
    }
#pragma unroll
    for (int ct = 0; ct < 8; ++ct) {
        const f32x4 s4 = *(const f32x4*)(scale + w * 128 + ct * 16 + quad * 4);
#pragma unroll
        for (int tt = 0; tt < 4; ++tt) {
            const int t = t0 + tt * 16 + l15;
            if (t < Tc) {
                f32x4 o = acc[tt][ct] * rstd[tt] * s4;
                *(f32x4*)(hidden + ((size_t)b * Tc + t) * Hc
                          + w * 128 + ct * 16 + quad * 4) = o;
            }
        }
    }
}

extern "C" void kernel_launch(void* const* d_in, const int* in_sizes, int n_in,
                              void* d_out, int out_size, void* d_ws, size_t ws_size,
                              hipStream_t stream) {
    const float* x       = (const float*)d_in[0];
    const int*   lengths = (const int*)d_in[1];
    const float* W       = (const float*)d_in[2];
    const float* bias    = (const float*)d_in[3];
    const float* scale   = (const float*)d_in[4];

    const size_t BTH = (size_t)Bc * Tc * Hc;   // 16,760,832
    float* out    = (float*)d_out;
    float* hidden = out;                        // output 0
    float* tl     = out + BTH;                  // output 1 (32 floats)
    float* tokens = out + BTH + Bc;             // output 2

    unsigned short* Wt = (unsigned short*)d_ws; // 512x512 bf16 = 512 KB, k-slice-packed

    {   // W -> Wt (transpose + bf16 + slice-pack) and token_lengths
        dim3 grid(Hc / 32, Hc / 32);            // (16,16)
        prep_kernel<<<grid, 256, 0, stream>>>(W, lengths, Wt, tl);
    }
    {   // fused tokens + GEMM + RMSNorm (balanced static tiles + fast path)
        dim3 grid(16, Bc);                      // 16 m-blocks x 32 batches
        fused_kernel<<<grid, 256, 0, stream>>>(x, lengths, Wt, bias, scale,
                                               hidden, tokens);
    }
}